// Round 10
// baseline (318.518 us; speedup 1.0000x reference)
//
#include <hip/hip_runtime.h>

typedef __bf16 bf16;
typedef __attribute__((ext_vector_type(8))) __bf16 bf16x8;
typedef __attribute__((ext_vector_type(4))) __bf16 bf16x4;
typedef __attribute__((ext_vector_type(4))) float f32x4;

#define NBATCH 8
#define NHEAD  12
#define SEQ    2048
#define DH     64
#define CDIM   768
#define MROWS  (NBATCH*SEQ)   /* 16384 */
#define NQKV   (3*CDIM)       /* 2304  */

__device__ __forceinline__ f32x4 mfma16(bf16x8 a, bf16x8 b, f32x4 c) {
  return __builtin_amdgcn_mfma_f32_16x16x32_bf16(a, b, c, 0, 0, 0);
}

__device__ __forceinline__ void gload_lds16(const void* g, void* l) {
  __builtin_amdgcn_global_load_lds((const __attribute__((address_space(1))) void*)g,
                                   (__attribute__((address_space(3))) void*)l,
                                   16, 0, 0);
}

// pack 2 f32 -> 1 u32 of 2 bf16 (T12; no builtin on gfx950, guide m240)
__device__ __forceinline__ unsigned cvt_pk_bf16(float lo, float hi) {
  unsigned r;
  asm("v_cvt_pk_bf16_f32 %0, %1, %2" : "=v"(r) : "v"(lo), "v"(hi));
  return r;
}

// raw v_exp_f32 (2^x). Register-only asm; args always <= 0 after first rescale.
__device__ __forceinline__ float exp2_raw(float x) {
  float r;
  asm("v_exp_f32 %0, %1" : "=v"(r) : "v"(x));
  return r;
}

// ---------------- fp32 -> bf16 convert ----------------
__global__ void cvt_bf16(const float* __restrict__ src, bf16* __restrict__ dst, int n8) {
  int i = blockIdx.x * 256 + threadIdx.x;
  if (i >= n8) return;
  const float4* s4 = (const float4*)src;
  float4 a = s4[2*i], c = s4[2*i+1];
  bf16x8 o;
  o[0]=(bf16)a.x; o[1]=(bf16)a.y; o[2]=(bf16)a.z; o[3]=(bf16)a.w;
  o[4]=(bf16)c.x; o[5]=(bf16)c.y; o[6]=(bf16)c.z; o[7]=(bf16)c.w;
  *(bf16x8*)(dst + (size_t)i*8) = o;
}

// ---------------- GEMM: C[M,N] = A[M,K] * B[N,K]^T (proven R1) -----------
template <int OUT_F32>
__global__ __launch_bounds__(256, 2)
void gemm_bt(const bf16* __restrict__ A, const bf16* __restrict__ Bm,
             void* __restrict__ Cout, const float* __restrict__ bias,
             int M, int Nn, int K) {
  __shared__ bf16 As[128*32];
  __shared__ bf16 Bs[128*32];
  const int tid = threadIdx.x, wid = tid >> 6, lane = tid & 63;
  const int g = lane >> 4, ln = lane & 15;
  const int ntn = Nn >> 7;
  const int gsz = 32 * ntn;
  const int grp = blockIdx.x / gsz;
  const int rem = blockIdx.x - grp * gsz;
  const int tm = grp * 32 + (rem & 31);
  const int tn = rem >> 5;
  const int m0 = tm << 7, n0 = tn << 7;
  const int wr = wid >> 1, wc = wid & 1;

  const int srow = lane >> 2;
  const int sslot = lane & 3;

  f32x4 acc[4][4] = {};

  const int nkt = K >> 5;
  for (int kt = 0; kt < nkt; ++kt) {
    if (kt) __syncthreads();
    #pragma unroll
    for (int i = 0; i < 2; ++i) {
      int c = wid * 2 + i;
      int row = c * 16 + srow;
      int colA = kt * 32 + ((sslot ^ (row & 3)) << 3);
      gload_lds16(A + (size_t)(m0 + row) * K + colA, &As[c * 512]);
      gload_lds16(Bm + (size_t)(n0 + row) * K + colA, &Bs[c * 512]);
    }
    __syncthreads();

    bf16x8 aF[4], bF[4];
    #pragma unroll
    for (int m = 0; m < 4; ++m) {
      int row = wr * 64 + m * 16 + ln;
      aF[m] = *(const bf16x8*)&As[row * 32 + ((g ^ (row & 3)) << 3)];
    }
    #pragma unroll
    for (int n = 0; n < 4; ++n) {
      int row = wc * 64 + n * 16 + ln;
      bF[n] = *(const bf16x8*)&Bs[row * 32 + ((g ^ (row & 3)) << 3)];
    }
    #pragma unroll
    for (int m = 0; m < 4; ++m)
      #pragma unroll
      for (int n = 0; n < 4; ++n)
        acc[m][n] = mfma16(aF[m], bF[n], acc[m][n]);
  }

  #pragma unroll
  for (int m = 0; m < 4; ++m) {
    int rowb = m0 + wr * 64 + m * 16 + g * 4;
    #pragma unroll
    for (int n = 0; n < 4; ++n) {
      int col = n0 + wc * 64 + n * 16 + ln;
      float bv = OUT_F32 ? bias[col] : 0.f;
      #pragma unroll
      for (int r = 0; r < 4; ++r) {
        if (OUT_F32)
          ((float*)Cout)[(size_t)(rowb + r) * Nn + col] = acc[m][n][r] + bv;
        else
          ((bf16*)Cout)[(size_t)(rowb + r) * Nn + col] = (bf16)acc[m][n][r];
      }
    }
  }
}

// ---------------- split: V section of qkv -> Vt ([B*H, D, N]) ------------
__global__ __launch_bounds__(256)
void split_v(const bf16* __restrict__ qkv, bf16* __restrict__ Vt) {
  __shared__ bf16 vlds[64 * 72];
  const int nt = blockIdx.x, bh = blockIdx.y;
  const int b = bh / NHEAD, h = bh % NHEAD;
  const int tid = threadIdx.x;
  const int nl = tid >> 2, quad = tid & 3;

  const bf16* s = qkv + ((size_t)(b * SEQ + nt * 64 + nl)) * NQKV + 2 * CDIM + h * DH + quad * 16;
  *(bf16x8*)&vlds[nl * 72 + quad * 16] = *(const bf16x8*)s;
  *(bf16x8*)&vlds[nl * 72 + quad * 16 + 8] = *(const bf16x8*)(s + 8);
  __syncthreads();
  const int dl = tid >> 2;
  bf16x8 w0, w1;
  #pragma unroll
  for (int j = 0; j < 8; ++j) {
    w0[j] = vlds[(quad * 16 + j) * 72 + dl];
    w1[j] = vlds[(quad * 16 + 8 + j) * 72 + dl];
  }
  bf16* d = Vt + ((size_t)bh * DH + dl) * SEQ + nt * 64 + quad * 16;
  *(bf16x8*)d = w0;
  *(bf16x8*)(d + 8) = w1;
}

// ---------------- flash attention fwd ------------------------------------
// R9 body + S-AHEAD pipeline (T15): QK^T(t+1) issues in the same scheduling
// zone as softmax(t) -- MFMA pipe hides the serial VALU softmax chain, which
// R8/R9 counters showed to be the limiter (no pipe >43% busy, occupancy 19%).
// 3 LDS buffers: PV(t) reads buf[t%3], QK^T(t+1) reads buf[(t+1)%3],
// stage(t+3) overwrites buf[t%3] after the tail barrier (2-iter prefetch
// lead). Two S register sets, parity-unrolled (static indexing, rule #20).
__global__ __launch_bounds__(128, 2)
void attn_fwd10(const bf16* __restrict__ qkv, const bf16* __restrict__ Vt,
                bf16* __restrict__ Oa) {
  __shared__ bf16 Ks[3 * 4096];
  __shared__ bf16 Vs[3 * 4096];
  const int tid = threadIdx.x, wid = tid >> 6, lane = tid & 63;
  const int g = lane >> 4, ln = lane & 15;
  const int qt = blockIdx.x, bh = blockIdx.y;
  const int b = bh / NHEAD, h = bh % NHEAD;

  // Q fragments (B role): wave wid owns q-rows qt*64 + wid*32 + {0..31}
  const bf16* QrowA = qkv + ((size_t)b * SEQ + qt * 64 + wid * 32 + ln) * NQKV + h * DH;
  const bf16* QrowB = QrowA + (size_t)16 * NQKV;
  const bf16x8 qA0 = *(const bf16x8*)(QrowA + g * 8);
  const bf16x8 qA1 = *(const bf16x8*)(QrowA + 32 + g * 8);
  const bf16x8 qB0 = *(const bf16x8*)(QrowB + g * 8);
  const bf16x8 qB1 = *(const bf16x8*)(QrowB + 32 + g * 8);

  // staging: 8 chunks of 8 position-rows x 64 cols; 4 chunks/wave each of K,V
  const int sr = lane >> 3, sl = lane & 7;
  const bf16* kp[4];
  const bf16* vp[4];
  int lofs[4];
  #pragma unroll
  for (int i = 0; i < 4; ++i) {
    const int c = wid * 4 + i;
    const int pr = c * 8 + sr;                 // position row 0..63
    const int sw = (sl ^ (pr & 7)) << 3;       // swizzled 16B slot (elems)
    // K row permutation: position p holds global key keyK(p) (verified R5-R9)
    const int keyK = ((pr >> 5) & 1) * 32 + ((pr >> 4) & 1) * 4 + ((pr >> 2) & 3) * 8 + (pr & 3);
    kp[i] = qkv + ((size_t)b * SEQ + keyK) * NQKV + CDIM + h * DH + sw;
    vp[i] = Vt + ((size_t)bh * DH + pr) * SEQ + sw;   // keyV = identity
    lofs[i] = c * 512;
  }
  const size_t KADV = (size_t)64 * NQKV;

  // loop-invariant LDS read offsets (position rows, same swizzle as staging)
  const int e7 = ln & 7;
  const int off0 = ln * 64 + ((g ^ e7) << 3);
  const int off1 = ln * 64 + (((4 | g) ^ e7) << 3);

  const bf16 one = (bf16)1.0f;
  const bf16x8 onesF = {one, one, one, one, one, one, one, one};

  f32x4 oA[4] = {}, oB[4] = {};
  f32x4 laccA = {0.f, 0.f, 0.f, 0.f}, laccB = {0.f, 0.f, 0.f, 0.f};
  float mA = -3.0e38f, mB = -3.0e38f;
  const float SC = 0.125f * 1.44269504088896f;  // D^-0.5 * log2(e)

  f32x4 sA0[4] = {}, sB0[4] = {}, sA1[4] = {}, sB1[4] = {};

#define STAGE(DST) do {                                           \
    _Pragma("unroll")                                             \
    for (int i = 0; i < 4; ++i) {                                 \
      gload_lds16(kp[i], &Ks[(DST) + lofs[i]]);                   \
      gload_lds16(vp[i], &Vs[(DST) + lofs[i]]);                   \
      kp[i] += KADV; vp[i] += 64;                                 \
    }                                                             \
  } while (0)

#define QKT(KOFS, SA, SB) do {                                    \
    const bf16* KsB_ = &Ks[(KOFS)];                               \
    _Pragma("unroll")                                             \
    for (int nt = 0; nt < 4; ++nt) {                              \
      bf16x8 kF0 = *(const bf16x8*)(KsB_ + off0 + nt * 1024);     \
      bf16x8 kF1 = *(const bf16x8*)(KsB_ + off1 + nt * 1024);     \
      SA[nt] = mfma16(kF0, qA0, SA[nt]);                          \
      SA[nt] = mfma16(kF1, qA1, SA[nt]);                          \
      SB[nt] = mfma16(kF0, qB0, SB[nt]);                          \
      SB[nt] = mfma16(kF1, qB1, SB[nt]);                          \
    }                                                             \
  } while (0)

  // prologue: stage tiles 0,1,2 (24 loads in flight); QK^T(0)
  STAGE(0);
  STAGE(4096);
  STAGE(8192);
  asm volatile("s_waitcnt vmcnt(16)" ::: "memory");   // tile 0 resident
  __builtin_amdgcn_s_barrier();
  __builtin_amdgcn_sched_barrier(0);
  QKT(0, sA0, sB0);

  const int NT = SEQ / 64;
  int cur = 0, nxt = 4096, stg = 8192;

#define ITER(T, SC_A, SC_B, SN_A, SN_B) do {                                  \
    if ((T) < NT - 2) asm volatile("s_waitcnt vmcnt(8)" ::: "memory");        \
    else              asm volatile("s_waitcnt vmcnt(0)" ::: "memory");        \
    __builtin_amdgcn_s_barrier();                                             \
    __builtin_amdgcn_sched_barrier(0);                                        \
    /* per-q max from current S (VALU + 4 shfl) */                            \
    float a0 = fmaxf(fmaxf(SC_A[0][0], SC_A[0][1]), fmaxf(SC_A[0][2], SC_A[0][3])); \
    float a1 = fmaxf(fmaxf(SC_A[1][0], SC_A[1][1]), fmaxf(SC_A[1][2], SC_A[1][3])); \
    float a2 = fmaxf(fmaxf(SC_A[2][0], SC_A[2][1]), fmaxf(SC_A[2][2], SC_A[2][3])); \
    float a3 = fmaxf(fmaxf(SC_A[3][0], SC_A[3][1]), fmaxf(SC_A[3][2], SC_A[3][3])); \
    float rA = fmaxf(fmaxf(a0, a1), fmaxf(a2, a3));                           \
    rA = fmaxf(rA, __shfl_xor(rA, 16, 64));                                   \
    rA = fmaxf(rA, __shfl_xor(rA, 32, 64));                                   \
    float b0_ = fmaxf(fmaxf(SC_B[0][0], SC_B[0][1]), fmaxf(SC_B[0][2], SC_B[0][3])); \
    float b1_ = fmaxf(fmaxf(SC_B[1][0], SC_B[1][1]), fmaxf(SC_B[1][2], SC_B[1][3])); \
    float b2_ = fmaxf(fmaxf(SC_B[2][0], SC_B[2][1]), fmaxf(SC_B[2][2], SC_B[2][3])); \
    float b3_ = fmaxf(fmaxf(SC_B[3][0], SC_B[3][1]), fmaxf(SC_B[3][2], SC_B[3][3])); \
    float rB = fmaxf(fmaxf(b0_, b1_), fmaxf(b2_, b3_));                       \
    rB = fmaxf(rB, __shfl_xor(rB, 16, 64));                                   \
    rB = fmaxf(rB, __shfl_xor(rB, 32, 64));                                   \
    const float rsA = rA * SC, rsB = rB * SC;                                 \
    __builtin_amdgcn_s_setprio(1);                                            \
    /* S-ahead: QK^T(t+1) -- independent of the softmax chain above/below */  \
    if ((T) < NT - 1) { QKT(nxt, SN_A, SN_B); }                               \
    /* defer-max (T13) */                                                     \
    if (__any(rsA > mA + 8.0f || rsB > mB + 8.0f)) {                          \
      float nmA = fmaxf(mA, rsA), nmB = fmaxf(mB, rsB);                       \
      float alA = exp2_raw(mA - nmA), alB = exp2_raw(mB - nmB);               \
      mA = nmA; mB = nmB;                                                     \
      float alrA[4], alrB[4];                                                 \
      _Pragma("unroll")                                                       \
      for (int r = 0; r < 4; ++r) {                                           \
        alrA[r] = __shfl(alA, g * 4 + r, 64);                                 \
        alrB[r] = __shfl(alB, g * 4 + r, 64);                                 \
      }                                                                       \
      _Pragma("unroll")                                                       \
      for (int dt = 0; dt < 4; ++dt)                                          \
        _Pragma("unroll")                                                     \
        for (int r = 0; r < 4; ++r) { oA[dt][r] *= alrA[r]; oB[dt][r] *= alrB[r]; } \
      _Pragma("unroll")                                                       \
      for (int r = 0; r < 4; ++r) { laccA[r] *= alrA[r]; laccB[r] *= alrB[r]; } \
    }                                                                         \
    /* P in-register (keyK makes S holdings the PV A-fragment) */             \
    bf16x8 pA[2], pB[2];                                                      \
    _Pragma("unroll")                                                         \
    for (int kk = 0; kk < 2; ++kk) {                                          \
      union { bf16x8 v; unsigned u[4]; } w;                                   \
      w.u[0] = cvt_pk_bf16(exp2_raw(fmaf(SC_A[2*kk][0], SC, -mA)),            \
                           exp2_raw(fmaf(SC_A[2*kk][1], SC, -mA)));           \
      w.u[1] = cvt_pk_bf16(exp2_raw(fmaf(SC_A[2*kk][2], SC, -mA)),            \
                           exp2_raw(fmaf(SC_A[2*kk][3], SC, -mA)));           \
      w.u[2] = cvt_pk_bf16(exp2_raw(fmaf(SC_A[2*kk+1][0], SC, -mA)),          \
                           exp2_raw(fmaf(SC_A[2*kk+1][1], SC, -mA)));         \
      w.u[3] = cvt_pk_bf16(exp2_raw(fmaf(SC_A[2*kk+1][2], SC, -mA)),          \
                           exp2_raw(fmaf(SC_A[2*kk+1][3], SC, -mA)));         \
      pA[kk] = w.v;                                                           \
      w.u[0] = cvt_pk_bf16(exp2_raw(fmaf(SC_B[2*kk][0], SC, -mB)),            \
                           exp2_raw(fmaf(SC_B[2*kk][1], SC, -mB)));           \
      w.u[1] = cvt_pk_bf16(exp2_raw(fmaf(SC_B[2*kk][2], SC, -mB)),            \
                           exp2_raw(fmaf(SC_B[2*kk][3], SC, -mB)));           \
      w.u[2] = cvt_pk_bf16(exp2_raw(fmaf(SC_B[2*kk+1][0], SC, -mB)),          \
                           exp2_raw(fmaf(SC_B[2*kk+1][1], SC, -mB)));         \
      w.u[3] = cvt_pk_bf16(exp2_raw(fmaf(SC_B[2*kk+1][2], SC, -mB)),          \
                           exp2_raw(fmaf(SC_B[2*kk+1][3], SC, -mB)));         \
      pB[kk] = w.v;                                                           \
    }                                                                         \
    /* zero current S for reuse as the next-next accumulator */               \
    _Pragma("unroll")                                                         \
    for (int nt = 0; nt < 4; ++nt) {                                          \
      f32x4 z = {0.f, 0.f, 0.f, 0.f};                                         \
      SC_A[nt] = z; SC_B[nt] = z;                                             \
    }                                                                         \
    /* O += P V ; l += P * ones */                                            \
    _Pragma("unroll")                                                         \
    for (int kk = 0; kk < 2; ++kk) {                                          \
      laccA = mfma16(pA[kk], onesF, laccA);                                   \
      laccB = mfma16(pB[kk], onesF, laccB);                                   \
      const int voff = (kk ? off1 : off0) + cur;                              \
      _Pragma("unroll")                                                       \
      for (int dt = 0; dt < 4; ++dt) {                                        \
        bf16x8 vF = *(const bf16x8*)(&Vs[0] + voff + dt * 1024);              \
        oA[dt] = mfma16(pA[kk], vF, oA[dt]);                                  \
        oB[dt] = mfma16(pB[kk], vF, oB[dt]);                                  \
      }                                                                       \
    }                                                                         \
    __builtin_amdgcn_s_setprio(0);                                            \
    __builtin_amdgcn_sched_barrier(0);                                        \
    __builtin_amdgcn_s_barrier();                                             \
    if ((T) + 3 < NT) { STAGE(cur); }                                         \
    { int tmp = cur; cur = nxt; nxt = stg; stg = tmp; }                       \
  } while (0)

  for (int t = 0; t < NT; t += 2) {
    ITER(t,     sA0, sB0, sA1, sB1);
    ITER(t + 1, sA1, sB1, sA0, sB0);
  }
#undef ITER
#undef QKT
#undef STAGE

  // normalize + store; lacc[r] = l[q=g*4+r] already in output layout
  float invA[4], invB[4];
  #pragma unroll
  for (int r = 0; r < 4; ++r) { invA[r] = 1.0f / laccA[r]; invB[r] = 1.0f / laccB[r]; }

  #pragma unroll
  for (int r = 0; r < 4; ++r) {
    bf16* OrA = Oa + ((size_t)b * SEQ + qt * 64 + wid * 32 + g * 4 + r) * CDIM + h * DH + ln;
    bf16* OrB = OrA + (size_t)16 * CDIM;
    #pragma unroll
    for (int dt = 0; dt < 4; ++dt) {
      OrA[dt * 16] = (bf16)(oA[dt][r] * invA[r]);
      OrB[dt * 16] = (bf16)(oB[dt][r] * invB[r]);
    }
  }
}

// ---------------- launch --------------------------------------------------
extern "C" void kernel_launch(void* const* d_in, const int* in_sizes, int n_in,
                              void* d_out, int out_size, void* d_ws, size_t ws_size,
                              hipStream_t stream) {
  const float* x      = (const float*)d_in[0];
  const float* w_qkv  = (const float*)d_in[1];
  const float* w_proj = (const float*)d_in[2];
  const float* b_proj = (const float*)d_in[3];

  char* ws = (char*)d_ws;
  bf16* x_bf    = (bf16*)(ws + 0);                    // 25165824
  bf16* wqkv_bf = (bf16*)(ws + 25165824);             // 3538944
  bf16* wproj_bf= (bf16*)(ws + 28704768);             // 1179648
  bf16* qkv     = (bf16*)(ws + 29884416);             // 75497472
  bf16* attn_o  = (bf16*)(ws + 105381888);            // 25165824
  bf16* Vtb     = (bf16*)(ws + 130547712);            // 25165824

  cvt_bf16<<<dim3((MROWS*CDIM/8 + 255)/256), 256, 0, stream>>>(x, x_bf, MROWS*CDIM/8);
  cvt_bf16<<<dim3((NQKV*CDIM/8 + 255)/256), 256, 0, stream>>>(w_qkv, wqkv_bf, NQKV*CDIM/8);
  cvt_bf16<<<dim3((CDIM*CDIM/8 + 255)/256), 256, 0, stream>>>(w_proj, wproj_bf, CDIM*CDIM/8);

  gemm_bt<0><<<dim3((MROWS/128)*(NQKV/128)), 256, 0, stream>>>(
      x_bf, wqkv_bf, qkv, nullptr, MROWS, NQKV, CDIM);

  split_v<<<dim3(SEQ/64, NBATCH*NHEAD), 256, 0, stream>>>(qkv, Vtb);

  attn_fwd10<<<dim3(SEQ/64, NBATCH*NHEAD), 128, 0, stream>>>(qkv, Vtb, attn_o);

  gemm_bt<1><<<dim3((MROWS/128)*(CDIM/128)), 256, 0, stream>>>(
      attn_o, wproj_bf, (float*)d_out, b_proj, MROWS, CDIM, CDIM);
}